// Round 6
// baseline (330.806 us; speedup 1.0000x reference)
//
#include <hip/hip_runtime.h>
#include <stdint.h>

typedef __attribute__((ext_vector_type(8))) short bf16x8;   // 8 bf16 in 4 VGPRs
typedef __attribute__((ext_vector_type(4))) float f32x4;
typedef __attribute__((address_space(1))) void as1_void;
typedef __attribute__((address_space(3))) void as3_void;

#define D_MODEL 1024
#define SEQ     2048
#define BATCH   4
#define HEADS   16
#define HDIM    64

// softmax scale: exp(s/32) = exp2(s * log2e/32); folded into Wq/bq at prep time
#define QSCALE 0.045084220029218407f

__device__ __forceinline__ ushort f2bf(float f) {
  union { float f; unsigned u; } v; v.f = f;
  unsigned u = v.u + 0x7fffu + ((v.u >> 16) & 1u);  // RNE
  return (ushort)(u >> 16);
}

__device__ __forceinline__ void gload_lds16(const void* g, void* l) {
  // width=16: emits global_load_lds_dwordx4; LDS dest = wave-uniform base + lane*16
  __builtin_amdgcn_global_load_lds((as1_void*)(uintptr_t)g, (as3_void*)l, 16, 0, 0);
}

// pack 8 floats -> bf16x8 (truncation) via v_perm
__device__ __forceinline__ bf16x8 pack8(float a0, float a1, float a2, float a3,
                                        float a4, float a5, float a6, float a7) {
  union { uint u[4]; bf16x8 v; } x;
  x.u[0] = __builtin_amdgcn_perm(__float_as_uint(a1), __float_as_uint(a0), 0x07060302);
  x.u[1] = __builtin_amdgcn_perm(__float_as_uint(a3), __float_as_uint(a2), 0x07060302);
  x.u[2] = __builtin_amdgcn_perm(__float_as_uint(a5), __float_as_uint(a4), 0x07060302);
  x.u[3] = __builtin_amdgcn_perm(__float_as_uint(a7), __float_as_uint(a6), 0x07060302);
  return x.v;
}

// ---------- fused prep: X->bf16 | W transpose->bf16 (Wq scaled) | bias concat ----------
__global__ void prep_kernel(const float* __restrict__ X,
                            const float* w0, const float* w1, const float* w2, const float* w3,
                            const float* __restrict__ bq, const float* __restrict__ bk,
                            const float* __restrict__ bv,
                            ushort* __restrict__ Xb, ushort* __restrict__ WT,
                            float* __restrict__ bcat) {
  __shared__ float tile[32][33];
  const int bx = blockIdx.x, t = threadIdx.x;
  if (bx < 8192) {                       // X fp32 -> bf16
    int i = bx * 256 + t;
    float4 f = reinterpret_cast<const float4*>(X)[i];
    ushort4 o;
    o.x = f2bf(f.x); o.y = f2bf(f.y); o.z = f2bf(f.z); o.w = f2bf(f.w);
    reinterpret_cast<ushort4*>(Xb)[i] = o;
  } else if (bx < 12288) {               // weight transpose: 4 weights x 1024 tiles
    int tz = bx - 8192;
    int z = tz >> 10;
    int xy = tz & 1023;
    int bxt = xy & 31, byt = xy >> 5;
    const float* w = (z == 0) ? w0 : (z == 1) ? w1 : (z == 2) ? w2 : w3;
    const float sc = (z == 0) ? QSCALE : 1.0f;
    ushort* o = WT + (size_t)z * D_MODEL * D_MODEL;
    int tx = t & 31, ty = t >> 5;
    int x = bxt * 32 + tx;
    int y0 = byt * 32;
    #pragma unroll
    for (int i = ty; i < 32; i += 8)
      tile[i][tx] = w[(size_t)(y0 + i) * D_MODEL + x];
    __syncthreads();
    #pragma unroll
    for (int i = ty; i < 32; i += 8)
      o[(size_t)(bxt * 32 + i) * D_MODEL + y0 + tx] = f2bf(tile[tx][i] * sc);
  } else {                               // bias concat (12 blocks)
    int i = (bx - 12288) * 256 + t;
    bcat[i] = (i < 1024) ? bq[i] * QSCALE : (i < 2048) ? bk[i - 1024] : bv[i - 2048];
  }
}

// ---------- QKV GEMM (m97 single-buffer): Q -> Qh[b][h][S][64], K -> Kh[b][h][S][64],
// V -> Vt[b][h][d][S] (keys permuted: col ck*64+c holds key ck*64+g(c),
// g(c)=(c&32)|((c&4)<<2)|((c>>1)&12)|(c&3)) ----------
__global__ __launch_bounds__(256) void gemm_qkv(const ushort* __restrict__ A, const ushort* __restrict__ BT,
                                                const float* __restrict__ bias,
                                                ushort* __restrict__ Qh, ushort* __restrict__ Kh,
                                                ushort* __restrict__ Vt) {
  __shared__ __align__(16) ushort As[128 * 32];
  __shared__ __align__(16) ushort Bs[128 * 32];
  const int K = D_MODEL;
  const int tid  = threadIdx.x;
  const int w    = tid >> 6;
  const int lane = tid & 63;
  const int lo   = lane & 15, quad = lane >> 4;
  const int m0 = blockIdx.y * 128, n0 = blockIdx.x * 128;
  const int ra = lane >> 2;
  const int ca = (lane & 3) * 8;
  const int wm = (w & 1) * 64, wn = (w >> 1) * 64;

  f32x4 acc[4][4];
  #pragma unroll
  for (int i = 0; i < 4; ++i)
    #pragma unroll
    for (int j = 0; j < 4; ++j) acc[i][j] = {0.f, 0.f, 0.f, 0.f};

  for (int k0 = 0; k0 < K; k0 += 32) {
    #pragma unroll
    for (int i = 0; i < 2; ++i) {
      const int j = w * 2 + i;
      gload_lds16(A  + (size_t)(m0 + j * 16 + ra) * K + k0 + ca, &As[j * 512]);
      gload_lds16(BT + (size_t)(n0 + j * 16 + ra) * K + k0 + ca, &Bs[j * 512]);
    }
    __syncthreads();
    bf16x8 af[4], bfv[4];
    #pragma unroll
    for (int mi = 0; mi < 4; ++mi) af[mi]  = *(const bf16x8*)&As[(wm + mi * 16 + lo) * 32 + quad * 8];
    #pragma unroll
    for (int ni = 0; ni < 4; ++ni) bfv[ni] = *(const bf16x8*)&Bs[(wn + ni * 16 + lo) * 32 + quad * 8];
    #pragma unroll
    for (int mi = 0; mi < 4; ++mi)
      #pragma unroll
      for (int ni = 0; ni < 4; ++ni)
        acc[mi][ni] = __builtin_amdgcn_mfma_f32_16x16x32_bf16(af[mi], bfv[ni], acc[mi][ni], 0, 0, 0);
    __syncthreads();
  }

  if (blockIdx.x < 16) {
    // Q,K part: head-blocked [b][h][S][64] stores
    #pragma unroll
    for (int ni = 0; ni < 4; ++ni) {
      const int col = n0 + wn + ni * 16 + lo;
      const float bv = bias[col];
      const int head = (col >> 6) & 15;
      const int d = col & 63;
      ushort* dst = (col < 1024) ? Qh : Kh;
      #pragma unroll
      for (int mi = 0; mi < 4; ++mi) {
        #pragma unroll
        for (int r = 0; r < 4; ++r) {
          const int row = m0 + wm + mi * 16 + quad * 4 + r;
          const int bidx = row >> 11, srow = row & 2047;
          dst[(size_t)((bidx * HEADS + head) * SEQ + srow) * HDIM + d] = f2bf(acc[mi][ni][r] + bv);
        }
      }
    }
  } else {
    // V part: permuted-transpose store into Vt[b][h][d][SEQ]
    #pragma unroll
    for (int ni = 0; ni < 4; ++ni) {
      const int col  = n0 + wn + ni * 16 + lo;
      const int vcol = col - 2048;
      const int hh = vcol >> 6, d = vcol & 63;
      const float bv = bias[col];
      #pragma unroll
      for (int mi = 0; mi < 4; ++mi) {
        const int base = m0 + wm + mi * 16;
        const int brow = base + quad * 4;
        const int bidx = brow >> 11;
        const int srow = brow & 2047;
        const int ck   = srow >> 6;
        const int c0   = (base & 32) + (quad << 3) + ((base >> 2) & 4);
        ushort e0 = f2bf(acc[mi][ni][0] + bv);
        ushort e1 = f2bf(acc[mi][ni][1] + bv);
        ushort e2 = f2bf(acc[mi][ni][2] + bv);
        ushort e3 = f2bf(acc[mi][ni][3] + bv);
        uint2 pk;
        pk.x = (uint)e0 | ((uint)e1 << 16);
        pk.y = (uint)e2 | ((uint)e3 << 16);
        *(uint2*)&Vt[(size_t)((bidx * HEADS + hh) * HDIM + d) * SEQ + ck * 64 + c0] = pk;
      }
    }
  }
}

// ---------- final projection GEMM (m97 single-buffer): fp32 out + bias ----------
__global__ __launch_bounds__(256) void gemm_bt_f32(const ushort* __restrict__ A, const ushort* __restrict__ BT,
                                                   const float* __restrict__ bias, float* __restrict__ C) {
  __shared__ __align__(16) ushort As[128 * 32];
  __shared__ __align__(16) ushort Bs[128 * 32];
  const int K = D_MODEL, N = D_MODEL;
  const int tid  = threadIdx.x;
  const int w    = tid >> 6;
  const int lane = tid & 63;
  const int lo   = lane & 15, quad = lane >> 4;
  const int m0 = blockIdx.y * 128, n0 = blockIdx.x * 128;
  const int ra = lane >> 2;
  const int ca = (lane & 3) * 8;
  const int wm = (w & 1) * 64, wn = (w >> 1) * 64;

  f32x4 acc[4][4];
  #pragma unroll
  for (int i = 0; i < 4; ++i)
    #pragma unroll
    for (int j = 0; j < 4; ++j) acc[i][j] = {0.f, 0.f, 0.f, 0.f};

  for (int k0 = 0; k0 < K; k0 += 32) {
    #pragma unroll
    for (int i = 0; i < 2; ++i) {
      const int j = w * 2 + i;
      gload_lds16(A  + (size_t)(m0 + j * 16 + ra) * K + k0 + ca, &As[j * 512]);
      gload_lds16(BT + (size_t)(n0 + j * 16 + ra) * K + k0 + ca, &Bs[j * 512]);
    }
    __syncthreads();
    bf16x8 af[4], bfv[4];
    #pragma unroll
    for (int mi = 0; mi < 4; ++mi) af[mi]  = *(const bf16x8*)&As[(wm + mi * 16 + lo) * 32 + quad * 8];
    #pragma unroll
    for (int ni = 0; ni < 4; ++ni) bfv[ni] = *(const bf16x8*)&Bs[(wn + ni * 16 + lo) * 32 + quad * 8];
    #pragma unroll
    for (int mi = 0; mi < 4; ++mi)
      #pragma unroll
      for (int ni = 0; ni < 4; ++ni)
        acc[mi][ni] = __builtin_amdgcn_mfma_f32_16x16x32_bf16(af[mi], bfv[ni], acc[mi][ni], 0, 0, 0);
    __syncthreads();
  }

  #pragma unroll
  for (int ni = 0; ni < 4; ++ni) {
    const int col = n0 + wn + ni * 16 + lo;
    const float bv = bias[col];
    #pragma unroll
    for (int mi = 0; mi < 4; ++mi) {
      #pragma unroll
      for (int r = 0; r < 4; ++r) {
        const int row = m0 + wm + mi * 16 + quad * 4 + r;
        C[(size_t)row * N + col] = acc[mi][ni][r] + bv;
      }
    }
  }
}

// ---------- flash attention, LDS-free: block = 256 q (4 waves x 64 q), 64-key chunks ----------
// grid (bh=64, qi=8): all 8 q-blocks of one (b,h) share linear-id mod 8 -> same XCD (L2 locality).
// S^T via mfma(A=K,B=Q); exp'd scores feed PV A-operand directly from registers.
// K/V fragments load straight from global (head-blocked Kh / permuted Vt); no LDS, no barriers.
__global__ __launch_bounds__(256) void attn_kernel(const ushort* __restrict__ Qh,
                                                   const ushort* __restrict__ Kh,
                                                   const ushort* __restrict__ Vt,
                                                   ushort* __restrict__ Og) {
  const int tid  = threadIdx.x;
  const int w    = tid >> 6, lane = tid & 63;
  const int lo   = lane & 15, quad = lane >> 4;
  const int bh = blockIdx.x;                   // b*16+h
  const int b = bh >> 4, h = bh & 15;
  const int qbase = blockIdx.y * 256 + w * 64;

  const ushort* Qbh = Qh + (size_t)bh * SEQ * HDIM;
  const ushort* Kbh = Kh + (size_t)bh * SEQ * HDIM;
  const ushort* Vbh = Vt + (size_t)bh * HDIM * SEQ;

  // Q fragments (B-operand layout: n=lo=q, k=quad*8+j); pre-scaled by QSCALE via Wq
  bf16x8 qf[4][2];
  #pragma unroll
  for (int qg = 0; qg < 4; ++qg) {
    const ushort* qp = Qbh + (size_t)(qbase + qg * 16 + lo) * HDIM + quad * 8;
    qf[qg][0] = *(const bf16x8*)(qp);
    qf[qg][1] = *(const bf16x8*)(qp + 32);
  }

  f32x4 acc[4][4];
  #pragma unroll
  for (int qg = 0; qg < 4; ++qg)
    #pragma unroll
    for (int t = 0; t < 4; ++t) acc[qg][t] = {0.f, 0.f, 0.f, 0.f};
  float lsum[4] = {0.f, 0.f, 0.f, 0.f};

  // K fragment loader (A-operand: m=key=sub*16+lo, k=d=hh*32+quad*8+j)
  bf16x8 kfa[4][2], kfb[4][2];
  auto load_kf = [&](int ck, bf16x8 kf[4][2]) {
    #pragma unroll
    for (int sub = 0; sub < 4; ++sub) {
      const ushort* kr = Kbh + (size_t)(ck * 64 + sub * 16 + lo) * HDIM + quad * 8;
      kf[sub][0] = *(const bf16x8*)(kr);
      kf[sub][1] = *(const bf16x8*)(kr + 32);
    }
  };

  // one chunk: issue vf loads first (oldest -> vmcnt waits don't drain the kf prefetch),
  // then prefetch kf(ck+1), then compute.
  auto do_chunk = [&](int ck, const bf16x8 kf[4][2], bf16x8 kfn[4][2]) {
    // V fragments (B-operand: n=d=t*16+lo, k=keyslot=hh*32+quad*8+j, keys permuted in Vt)
    bf16x8 vf[4][2];
    #pragma unroll
    for (int t = 0; t < 4; ++t) {
      const ushort* vr = Vbh + (size_t)(t * 16 + lo) * SEQ + ck * 64 + quad * 8;
      vf[t][0] = *(const bf16x8*)(vr);
      vf[t][1] = *(const bf16x8*)(vr + 32);
    }
    const int ckn = (ck + 1 < SEQ / 64) ? ck + 1 : ck;   // clamp (last prefetch is dead)
    load_kf(ckn, kfn);

    // phase A: S^T per q-group, exp + pack in registers
    bf16x8 af[4][2];
    #pragma unroll
    for (int qg = 0; qg < 4; ++qg) {
      f32x4 s[4];
      #pragma unroll
      for (int sub = 0; sub < 4; ++sub) s[sub] = {0.f, 0.f, 0.f, 0.f};
      #pragma unroll
      for (int sub = 0; sub < 4; ++sub) {
        s[sub] = __builtin_amdgcn_mfma_f32_16x16x32_bf16(kf[sub][0], qf[qg][0], s[sub], 0, 0, 0);
        s[sub] = __builtin_amdgcn_mfma_f32_16x16x32_bf16(kf[sub][1], qf[qg][1], s[sub], 0, 0, 0);
      }
      float p[4][4];
      #pragma unroll
      for (int sub = 0; sub < 4; ++sub)
        #pragma unroll
        for (int r = 0; r < 4; ++r) p[sub][r] = __builtin_amdgcn_exp2f(s[sub][r]);
      float t0 = 0.f;
      #pragma unroll
      for (int sub = 0; sub < 4; ++sub)
        t0 += (p[sub][0] + p[sub][1]) + (p[sub][2] + p[sub][3]);
      lsum[qg] += t0;
      af[qg][0] = pack8(p[0][0], p[0][1], p[0][2], p[0][3], p[1][0], p[1][1], p[1][2], p[1][3]);
      af[qg][1] = pack8(p[2][0], p[2][1], p[2][2], p[2][3], p[3][0], p[3][1], p[3][2], p[3][3]);
    }

    // phase B: PV (A = exp'd scores from registers, B = V fragments)
    #pragma unroll
    for (int t = 0; t < 4; ++t)
      #pragma unroll
      for (int hh = 0; hh < 2; ++hh)
        #pragma unroll
        for (int qg = 0; qg < 4; ++qg)
          acc[qg][t] = __builtin_amdgcn_mfma_f32_16x16x32_bf16(af[qg][hh], vf[t][hh], acc[qg][t], 0, 0, 0);
  };

  load_kf(0, kfa);
  for (int ck = 0; ck < SEQ / 64; ck += 2) {
    do_chunk(ck,     kfa, kfb);
    do_chunk(ck + 1, kfb, kfa);
  }

  // epilogue: lsum lives at lane lo = q; reduce across quads, redistribute, store
  #pragma unroll
  for (int qg = 0; qg < 4; ++qg) {
    float v = lsum[qg];
    v += __shfl_xor(v, 16);
    v += __shfl_xor(v, 32);
    float linv[4];
    #pragma unroll
    for (int r = 0; r < 4; ++r) linv[r] = 1.0f / __shfl(v, quad * 4 + r);
    #pragma unroll
    for (int t = 0; t < 4; ++t)
      #pragma unroll
      for (int r = 0; r < 4; ++r)
        Og[(size_t)(b * SEQ + qbase + qg * 16 + quad * 4 + r) * D_MODEL + h * HDIM + t * 16 + lo] =
            f2bf(acc[qg][t][r] * linv[r]);
  }
}

extern "C" void kernel_launch(void* const* d_in, const int* in_sizes, int n_in,
                              void* d_out, int out_size, void* d_ws, size_t ws_size,
                              hipStream_t stream) {
  const float* X  = (const float*)d_in[0];
  const float* Wq = (const float*)d_in[1];
  const float* bq = (const float*)d_in[2];
  const float* Wk = (const float*)d_in[3];
  const float* bk = (const float*)d_in[4];
  const float* Wv = (const float*)d_in[5];
  const float* bv = (const float*)d_in[6];
  const float* Wo = (const float*)d_in[7];
  const float* bo = (const float*)d_in[8];
  float* out = (float*)d_out;
  char* ws = (char*)d_ws;

  // workspace (88 MB):
  //   [0,16M)   Xb  (bf16 X)
  //   [16,24M)  WT  (4x bf16 transposed weights q|k|v|o; Wq pre-scaled)
  //   [24,40M)  Qh  bf16 [b][h][S][64]
  //   [40,56M)  Kh  bf16 [b][h][S][64]
  //   [56,72M)  Vt  bf16 [b][h][64][S] (permuted keys)
  //   [72,88M)  Ob  bf16 [8192][1024]; head transiently holds bcat (dead before attn writes Ob)
  ushort* Xb  = (ushort*)(ws);
  ushort* WT  = (ushort*)(ws + 16777216);
  ushort* Qhb = (ushort*)(ws + 25165824);
  ushort* Khb = (ushort*)(ws + 41943040);
  ushort* Vtb = (ushort*)(ws + 58720256);
  ushort* Ob  = (ushort*)(ws + 75497472);
  float*  bcat = (float*)(ws + 75497472);
  const int WSTRIDE = D_MODEL * D_MODEL;

  // 1) fused prep: X->bf16, weight transposes, bias concat
  prep_kernel<<<12300, 256, 0, stream>>>(X, Wq, Wk, Wv, Wo, bq, bk, bv, Xb, WT, bcat);

  // 2) fused QKV projection; Q/K head-blocked, V written straight to Vt (permuted transpose)
  gemm_qkv<<<dim3(24, 64), 256, 0, stream>>>(Xb, WT, bcat, Qhb, Khb, Vtb);

  // 3) flash attention (LDS-free, XCD-swizzled grid)
  attn_kernel<<<dim3(BATCH * HEADS, SEQ / 256), 256, 0, stream>>>(Qhb, Khb, Vtb, Ob);

  // 4) output projection (fp32 out + bias)
  gemm_bt_f32<<<dim3(8, 64), 256, 0, stream>>>(Ob, WT + 3 * WSTRIDE, bo, out);
}

// Round 7
// 287.130 us; speedup vs baseline: 1.1521x; 1.1521x over previous
//
#include <hip/hip_runtime.h>
#include <stdint.h>

typedef __attribute__((ext_vector_type(8))) short bf16x8;   // 8 bf16 in 4 VGPRs
typedef __attribute__((ext_vector_type(4))) float f32x4;
typedef __attribute__((address_space(1))) void as1_void;
typedef __attribute__((address_space(3))) void as3_void;

#define D_MODEL 1024
#define SEQ     2048
#define BATCH   4
#define HEADS   16
#define HDIM    64

// softmax scale: exp(s/32) = exp2(s * log2e/32); folded into Wq/bq at prep time
#define QSCALE 0.045084220029218407f

__device__ __forceinline__ ushort f2bf(float f) {
  union { float f; unsigned u; } v; v.f = f;
  unsigned u = v.u + 0x7fffu + ((v.u >> 16) & 1u);  // RNE
  return (ushort)(u >> 16);
}

__device__ __forceinline__ void gload_lds16(const void* g, void* l) {
  // width=16: emits global_load_lds_dwordx4; LDS dest = wave-uniform base + lane*16
  __builtin_amdgcn_global_load_lds((as1_void*)(uintptr_t)g, (as3_void*)l, 16, 0, 0);
}

// pack 8 floats -> bf16x8 (truncation) via v_perm
__device__ __forceinline__ bf16x8 pack8(float a0, float a1, float a2, float a3,
                                        float a4, float a5, float a6, float a7) {
  union { uint u[4]; bf16x8 v; } x;
  x.u[0] = __builtin_amdgcn_perm(__float_as_uint(a1), __float_as_uint(a0), 0x07060302);
  x.u[1] = __builtin_amdgcn_perm(__float_as_uint(a3), __float_as_uint(a2), 0x07060302);
  x.u[2] = __builtin_amdgcn_perm(__float_as_uint(a5), __float_as_uint(a4), 0x07060302);
  x.u[3] = __builtin_amdgcn_perm(__float_as_uint(a7), __float_as_uint(a6), 0x07060302);
  return x.v;
}

// ---------- fused prep: X->bf16 | W transpose->bf16 (Wq scaled) | bias concat ----------
__global__ void prep_kernel(const float* __restrict__ X,
                            const float* w0, const float* w1, const float* w2, const float* w3,
                            const float* __restrict__ bq, const float* __restrict__ bk,
                            const float* __restrict__ bv,
                            ushort* __restrict__ Xb, ushort* __restrict__ WT,
                            float* __restrict__ bcat) {
  __shared__ float tile[32][33];
  const int bx = blockIdx.x, t = threadIdx.x;
  if (bx < 8192) {                       // X fp32 -> bf16
    int i = bx * 256 + t;
    float4 f = reinterpret_cast<const float4*>(X)[i];
    ushort4 o;
    o.x = f2bf(f.x); o.y = f2bf(f.y); o.z = f2bf(f.z); o.w = f2bf(f.w);
    reinterpret_cast<ushort4*>(Xb)[i] = o;
  } else if (bx < 12288) {               // weight transpose: 4 weights x 1024 tiles
    int tz = bx - 8192;
    int z = tz >> 10;
    int xy = tz & 1023;
    int bxt = xy & 31, byt = xy >> 5;
    const float* w = (z == 0) ? w0 : (z == 1) ? w1 : (z == 2) ? w2 : w3;
    const float sc = (z == 0) ? QSCALE : 1.0f;
    ushort* o = WT + (size_t)z * D_MODEL * D_MODEL;
    int tx = t & 31, ty = t >> 5;
    int x = bxt * 32 + tx;
    int y0 = byt * 32;
    #pragma unroll
    for (int i = ty; i < 32; i += 8)
      tile[i][tx] = w[(size_t)(y0 + i) * D_MODEL + x];
    __syncthreads();
    #pragma unroll
    for (int i = ty; i < 32; i += 8)
      o[(size_t)(bxt * 32 + i) * D_MODEL + y0 + tx] = f2bf(tile[tx][i] * sc);
  } else {                               // bias concat (12 blocks)
    int i = (bx - 12288) * 256 + t;
    bcat[i] = (i < 1024) ? bq[i] * QSCALE : (i < 2048) ? bk[i - 1024] : bv[i - 2048];
  }
}

// ---------- QKV GEMM (m97 single-buffer): Q -> Qh[b][h][S][64], K -> Kh[b][h][S][64],
// V -> Vt[b][h][d][S] (keys permuted per 64-chunk: col ck*64+c holds key ck*64+g(c),
// g(c)=(c&32)|((c&4)<<2)|((c>>1)&12)|(c&3)) ----------
__global__ __launch_bounds__(256) void gemm_qkv(const ushort* __restrict__ A, const ushort* __restrict__ BT,
                                                const float* __restrict__ bias,
                                                ushort* __restrict__ Qh, ushort* __restrict__ Kh,
                                                ushort* __restrict__ Vt) {
  __shared__ __align__(16) ushort As[128 * 32];
  __shared__ __align__(16) ushort Bs[128 * 32];
  const int K = D_MODEL;
  const int tid  = threadIdx.x;
  const int w    = tid >> 6;
  const int lane = tid & 63;
  const int lo   = lane & 15, quad = lane >> 4;
  const int m0 = blockIdx.y * 128, n0 = blockIdx.x * 128;
  const int ra = lane >> 2;
  const int ca = (lane & 3) * 8;
  const int wm = (w & 1) * 64, wn = (w >> 1) * 64;

  f32x4 acc[4][4];
  #pragma unroll
  for (int i = 0; i < 4; ++i)
    #pragma unroll
    for (int j = 0; j < 4; ++j) acc[i][j] = {0.f, 0.f, 0.f, 0.f};

  for (int k0 = 0; k0 < K; k0 += 32) {
    #pragma unroll
    for (int i = 0; i < 2; ++i) {
      const int j = w * 2 + i;
      gload_lds16(A  + (size_t)(m0 + j * 16 + ra) * K + k0 + ca, &As[j * 512]);
      gload_lds16(BT + (size_t)(n0 + j * 16 + ra) * K + k0 + ca, &Bs[j * 512]);
    }
    __syncthreads();
    bf16x8 af[4], bfv[4];
    #pragma unroll
    for (int mi = 0; mi < 4; ++mi) af[mi]  = *(const bf16x8*)&As[(wm + mi * 16 + lo) * 32 + quad * 8];
    #pragma unroll
    for (int ni = 0; ni < 4; ++ni) bfv[ni] = *(const bf16x8*)&Bs[(wn + ni * 16 + lo) * 32 + quad * 8];
    #pragma unroll
    for (int mi = 0; mi < 4; ++mi)
      #pragma unroll
      for (int ni = 0; ni < 4; ++ni)
        acc[mi][ni] = __builtin_amdgcn_mfma_f32_16x16x32_bf16(af[mi], bfv[ni], acc[mi][ni], 0, 0, 0);
    __syncthreads();
  }

  if (blockIdx.x < 16) {
    // Q,K part: head-blocked [b][h][S][64] stores
    #pragma unroll
    for (int ni = 0; ni < 4; ++ni) {
      const int col = n0 + wn + ni * 16 + lo;
      const float bv = bias[col];
      const int head = (col >> 6) & 15;
      const int d = col & 63;
      ushort* dst = (col < 1024) ? Qh : Kh;
      #pragma unroll
      for (int mi = 0; mi < 4; ++mi) {
        #pragma unroll
        for (int r = 0; r < 4; ++r) {
          const int row = m0 + wm + mi * 16 + quad * 4 + r;
          const int bidx = row >> 11, srow = row & 2047;
          dst[(size_t)((bidx * HEADS + head) * SEQ + srow) * HDIM + d] = f2bf(acc[mi][ni][r] + bv);
        }
      }
    }
  } else {
    // V part: permuted-transpose store into Vt[b][h][d][SEQ]
    #pragma unroll
    for (int ni = 0; ni < 4; ++ni) {
      const int col  = n0 + wn + ni * 16 + lo;
      const int vcol = col - 2048;
      const int hh = vcol >> 6, d = vcol & 63;
      const float bv = bias[col];
      #pragma unroll
      for (int mi = 0; mi < 4; ++mi) {
        const int base = m0 + wm + mi * 16;
        const int brow = base + quad * 4;
        const int bidx = brow >> 11;
        const int srow = brow & 2047;
        const int ck   = srow >> 6;
        const int c0   = (base & 32) + (quad << 3) + ((base >> 2) & 4);
        ushort e0 = f2bf(acc[mi][ni][0] + bv);
        ushort e1 = f2bf(acc[mi][ni][1] + bv);
        ushort e2 = f2bf(acc[mi][ni][2] + bv);
        ushort e3 = f2bf(acc[mi][ni][3] + bv);
        uint2 pk;
        pk.x = (uint)e0 | ((uint)e1 << 16);
        pk.y = (uint)e2 | ((uint)e3 << 16);
        *(uint2*)&Vt[(size_t)((bidx * HEADS + hh) * HDIM + d) * SEQ + ck * 64 + c0] = pk;
      }
    }
  }
}

// ---------- final projection GEMM (m97 single-buffer): fp32 out + bias ----------
__global__ __launch_bounds__(256) void gemm_bt_f32(const ushort* __restrict__ A, const ushort* __restrict__ BT,
                                                   const float* __restrict__ bias, float* __restrict__ C) {
  __shared__ __align__(16) ushort As[128 * 32];
  __shared__ __align__(16) ushort Bs[128 * 32];
  const int K = D_MODEL, N = D_MODEL;
  const int tid  = threadIdx.x;
  const int w    = tid >> 6;
  const int lane = tid & 63;
  const int lo   = lane & 15, quad = lane >> 4;
  const int m0 = blockIdx.y * 128, n0 = blockIdx.x * 128;
  const int ra = lane >> 2;
  const int ca = (lane & 3) * 8;
  const int wm = (w & 1) * 64, wn = (w >> 1) * 64;

  f32x4 acc[4][4];
  #pragma unroll
  for (int i = 0; i < 4; ++i)
    #pragma unroll
    for (int j = 0; j < 4; ++j) acc[i][j] = {0.f, 0.f, 0.f, 0.f};

  for (int k0 = 0; k0 < K; k0 += 32) {
    #pragma unroll
    for (int i = 0; i < 2; ++i) {
      const int j = w * 2 + i;
      gload_lds16(A  + (size_t)(m0 + j * 16 + ra) * K + k0 + ca, &As[j * 512]);
      gload_lds16(BT + (size_t)(n0 + j * 16 + ra) * K + k0 + ca, &Bs[j * 512]);
    }
    __syncthreads();
    bf16x8 af[4], bfv[4];
    #pragma unroll
    for (int mi = 0; mi < 4; ++mi) af[mi]  = *(const bf16x8*)&As[(wm + mi * 16 + lo) * 32 + quad * 8];
    #pragma unroll
    for (int ni = 0; ni < 4; ++ni) bfv[ni] = *(const bf16x8*)&Bs[(wn + ni * 16 + lo) * 32 + quad * 8];
    #pragma unroll
    for (int mi = 0; mi < 4; ++mi)
      #pragma unroll
      for (int ni = 0; ni < 4; ++ni)
        acc[mi][ni] = __builtin_amdgcn_mfma_f32_16x16x32_bf16(af[mi], bfv[ni], acc[mi][ni], 0, 0, 0);
    __syncthreads();
  }

  #pragma unroll
  for (int ni = 0; ni < 4; ++ni) {
    const int col = n0 + wn + ni * 16 + lo;
    const float bv = bias[col];
    #pragma unroll
    for (int mi = 0; mi < 4; ++mi) {
      #pragma unroll
      for (int r = 0; r < 4; ++r) {
        const int row = m0 + wm + mi * 16 + quad * 4 + r;
        C[(size_t)row * N + col] = acc[mi][ni][r] + bv;
      }
    }
  }
}

// ---------- flash attention: LDS-staged, 128-key chunks processed as two 64-key halves ----------
// block = 256 q (4 waves x 64 q), grid (bh=64, qi=8) -> all 8 q-blocks of one (b,h) on one XCD.
// S^T via mfma(A=K,B=Q); exp'd scores feed the PV A-operand directly from registers
// (key order matched by the Vt store permutation in gemm_qkv).
__global__ __launch_bounds__(256, 2) void attn_kernel(const ushort* __restrict__ Qh,
                                                      const ushort* __restrict__ Kh,
                                                      const ushort* __restrict__ Vt,
                                                      ushort* __restrict__ Og) {
  __shared__ __align__(16) ushort Ks[128 * 64];   // [key][64 d], seg-swizzled (8 segs, key&7)
  __shared__ __align__(16) ushort Vs[64 * 128];   // [d][128 key-slots], seg-swizzled (16 segs, d&15)

  const int tid  = threadIdx.x;
  const int w    = tid >> 6, lane = tid & 63;
  const int lo   = lane & 15, quad = lane >> 4;
  const int bh = blockIdx.x;                   // b*16+h
  const int b = bh >> 4, h = bh & 15;
  const int qbase = blockIdx.y * 256 + w * 64;

  const ushort* Qbh = Qh + (size_t)bh * SEQ * HDIM;
  const ushort* Kbh = Kh + (size_t)bh * SEQ * HDIM;
  const ushort* Vbh = Vt + (size_t)bh * HDIM * SEQ;

  // Q fragments (B-operand layout: n=lo=q, k=quad*8+j); pre-scaled by QSCALE via Wq
  bf16x8 qf[4][2];
  #pragma unroll
  for (int qg = 0; qg < 4; ++qg) {
    const ushort* qp = Qbh + (size_t)(qbase + qg * 16 + lo) * HDIM + quad * 8;
    qf[qg][0] = *(const bf16x8*)(qp);
    qf[qg][1] = *(const bf16x8*)(qp + 32);
  }

  f32x4 acc[4][4];
  #pragma unroll
  for (int qg = 0; qg < 4; ++qg)
    #pragma unroll
    for (int t = 0; t < 4; ++t) acc[qg][t] = {0.f, 0.f, 0.f, 0.f};
  float lsum[4] = {0.f, 0.f, 0.f, 0.f};

  // staging lane roles (chunk-invariant)
  const int krow = lane >> 3;                 // 0..7 within an 8-row group (128B rows)
  const int kseg = lane & 7;
  const int vrow = lane >> 4;                 // 0..3 within a 4-row group (256B rows)
  const int vseg = lane & 15;

  for (int ck = 0; ck < SEQ / 128; ++ck) {
    __syncthreads();   // previous chunk fully consumed
    #pragma unroll
    for (int i = 0; i < 4; ++i) {
      const int jj = w * 4 + i;               // 0..15 staging slot (wave-uniform)
      {  // Ks: slot = 8 key-rows of 128B; phys seg ps holds logical seg ps^(r&7)
        const int r = jj * 8 + krow;
        const int gs = kseg ^ (r & 7);
        gload_lds16(Kbh + (size_t)(ck * 128 + r) * HDIM + gs * 8, &Ks[jj * 512]);
      }
      {  // Vs: slot = 4 d-rows of 256B; phys seg ps holds logical seg ps^(d&15)
        const int d = jj * 4 + vrow;
        const int gs = vseg ^ (d & 15);
        gload_lds16(Vbh + (size_t)d * SEQ + ck * 128 + gs * 8, &Vs[jj * 512]);
      }
    }
    __syncthreads();

    #pragma unroll
    for (int x = 0; x < 2; ++x) {            // two 64-key halves
      // K fragments (A-operand: m=key=sub*16+lo, k=d=hh*32+quad*8+j)
      bf16x8 kf[4][2];
      #pragma unroll
      for (int sub = 0; sub < 4; ++sub) {
        const ushort* kr = &Ks[(x * 64 + sub * 16 + lo) * 64];
        kf[sub][0] = *(const bf16x8*)(kr + ((quad ^ (lo & 7)) * 8));
        kf[sub][1] = *(const bf16x8*)(kr + (((4 + quad) ^ (lo & 7)) * 8));
      }

      // phase A: S^T per q-group, exp + pack in registers
      bf16x8 af[4][2];
      #pragma unroll
      for (int qg = 0; qg < 4; ++qg) {
        f32x4 s[4];
        #pragma unroll
        for (int sub = 0; sub < 4; ++sub) s[sub] = {0.f, 0.f, 0.f, 0.f};
        #pragma unroll
        for (int sub = 0; sub < 4; ++sub) {
          s[sub] = __builtin_amdgcn_mfma_f32_16x16x32_bf16(kf[sub][0], qf[qg][0], s[sub], 0, 0, 0);
          s[sub] = __builtin_amdgcn_mfma_f32_16x16x32_bf16(kf[sub][1], qf[qg][1], s[sub], 0, 0, 0);
        }
        float p[4][4];
        #pragma unroll
        for (int sub = 0; sub < 4; ++sub)
          #pragma unroll
          for (int r = 0; r < 4; ++r) p[sub][r] = __builtin_amdgcn_exp2f(s[sub][r]);
        float t0 = 0.f;
        #pragma unroll
        for (int sub = 0; sub < 4; ++sub)
          t0 += (p[sub][0] + p[sub][1]) + (p[sub][2] + p[sub][3]);
        lsum[qg] += t0;
        af[qg][0] = pack8(p[0][0], p[0][1], p[0][2], p[0][3], p[1][0], p[1][1], p[1][2], p[1][3]);
        af[qg][1] = pack8(p[2][0], p[2][1], p[2][2], p[2][3], p[3][0], p[3][1], p[3][2], p[3][3]);
      }

      // phase B: PV (A = exp'd scores from registers, B = V^T from LDS)
      #pragma unroll
      for (int t = 0; t < 4; ++t) {
        const ushort* vr = &Vs[(t * 16 + lo) * 128 + x * 0];   // x folded into seg index below
        #pragma unroll
        for (int hh = 0; hh < 2; ++hh) {
          bf16x8 vf = *(const bf16x8*)(vr + (((x * 8 + hh * 4 + quad) ^ lo) * 8));
          #pragma unroll
          for (int qg = 0; qg < 4; ++qg)
            acc[qg][t] = __builtin_amdgcn_mfma_f32_16x16x32_bf16(af[qg][hh], vf, acc[qg][t], 0, 0, 0);
        }
      }
    }
  }

  // epilogue: lsum lives at lane lo = q; reduce across quads, redistribute, store
  #pragma unroll
  for (int qg = 0; qg < 4; ++qg) {
    float v = lsum[qg];
    v += __shfl_xor(v, 16);
    v += __shfl_xor(v, 32);
    float linv[4];
    #pragma unroll
    for (int r = 0; r < 4; ++r) linv[r] = 1.0f / __shfl(v, quad * 4 + r);
    #pragma unroll
    for (int t = 0; t < 4; ++t)
      #pragma unroll
      for (int r = 0; r < 4; ++r)
        Og[(size_t)(b * SEQ + qbase + qg * 16 + quad * 4 + r) * D_MODEL + h * HDIM + t * 16 + lo] =
            f2bf(acc[qg][t][r] * linv[r]);
  }
}

extern "C" void kernel_launch(void* const* d_in, const int* in_sizes, int n_in,
                              void* d_out, int out_size, void* d_ws, size_t ws_size,
                              hipStream_t stream) {
  const float* X  = (const float*)d_in[0];
  const float* Wq = (const float*)d_in[1];
  const float* bq = (const float*)d_in[2];
  const float* Wk = (const float*)d_in[3];
  const float* bk = (const float*)d_in[4];
  const float* Wv = (const float*)d_in[5];
  const float* bv = (const float*)d_in[6];
  const float* Wo = (const float*)d_in[7];
  const float* bo = (const float*)d_in[8];
  float* out = (float*)d_out;
  char* ws = (char*)d_ws;

  // workspace (88 MB):
  //   [0,16M)   Xb  (bf16 X)
  //   [16,24M)  WT  (4x bf16 transposed weights q|k|v|o; Wq pre-scaled)
  //   [24,40M)  Qh  bf16 [b][h][S][64]
  //   [40,56M)  Kh  bf16 [b][h][S][64]
  //   [56,72M)  Vt  bf16 [b][h][64][S] (permuted keys)
  //   [72,88M)  Ob  bf16 [8192][1024]; head transiently holds bcat (dead before attn writes Ob)
  ushort* Xb  = (ushort*)(ws);
  ushort* WT  = (ushort*)(ws + 16777216);
  ushort* Qhb = (ushort*)(ws + 25165824);
  ushort* Khb = (ushort*)(ws + 41943040);
  ushort* Vtb = (ushort*)(ws + 58720256);
  ushort* Ob  = (ushort*)(ws + 75497472);
  float*  bcat = (float*)(ws + 75497472);
  const int WSTRIDE = D_MODEL * D_MODEL;

  // 1) fused prep: X->bf16, weight transposes, bias concat
  prep_kernel<<<12300, 256, 0, stream>>>(X, Wq, Wk, Wv, Wo, bq, bk, bv, Xb, WT, bcat);

  // 2) fused QKV projection; Q/K head-blocked, V written straight to Vt (permuted transpose)
  gemm_qkv<<<dim3(24, 64), 256, 0, stream>>>(Xb, WT, bcat, Qhb, Khb, Vtb);

  // 3) flash attention (LDS-staged, 128-key chunks, XCD-swizzled grid)
  attn_kernel<<<dim3(BATCH * HEADS, SEQ / 256), 256, 0, stream>>>(Qhb, Khb, Vtb, Ob);

  // 4) output projection (fp32 out + bias)
  gemm_bt_f32<<<dim3(8, 64), 256, 0, stream>>>(Ob, WT + 3 * WSTRIDE, bo, out);
}